// Round 1
// baseline (1880.062 us; speedup 1.0000x reference)
//
#include <hip/hip_runtime.h>
#include <cstdint>
#include <cstddef>

// Problem constants (fixed by the reference)
#define B_      32
#define N_      8400
#define C_      80
#define NC      672000        // N_*C_
#define NBINS   4096
#define TOPK    1024
#define MAXDET  300
#define CANDCAP 4096
#define CHUNK   16000
#define NCHUNK  42            // 42*16000 == 672000

// Workspace layout (bytes)
#define WS_HIST      0              // 32*4096*4  = 524288
#define WS_CANDCNT   524288         // 32*4       = 128
#define WS_CUTBIN    524416         // 32*4       = 128
#define WS_CANDKEYS  524544         // 32*4096*8  = 1048576
#define WS_TOPSCORE  1573120        // 32*1024*4  = 131072
#define WS_TOPBOX    1704192        // 32*1024*16 = 524288
#define WS_TOPCLS    2228480        // 32*1024*4  = 131072
#define WS_KEEP      2359552        // 32*1024*4  = 131072
#define WS_TOTAL     2490624

// Output layout (float32, concatenated): boxes[32][300][4], scores[32][300],
// labels[32][300], n_valid[32]
#define OUT_SCORES  38400
#define OUT_LABELS  48000
#define OUT_NVALID  57600

// ---------------------------------------------------------------------------
// K1: per-batch histogram of bin = floor(v*4096), v = (s > 0.001 ? s : 0)
__global__ __launch_bounds__(256) void hist_kernel(const float* __restrict__ scores,
                                                   unsigned* __restrict__ hist) {
    __shared__ unsigned h[NBINS];
    int b = blockIdx.x;
    int chunk = blockIdx.y;
    for (int i = threadIdx.x; i < NBINS; i += 256) h[i] = 0;
    __syncthreads();
    const float* s = scores + (size_t)b * NC;
    int start = chunk * CHUNK;
    int end = start + CHUNK;
    for (int i = start + threadIdx.x; i < end; i += 256) {
        float v = s[i];
        v = (v > 0.001f) ? v : 0.0f;
        int bin = (int)(v * 4096.0f);       // exact: v * 2^12
        bin = bin > (NBINS - 1) ? (NBINS - 1) : bin;
        atomicAdd(&h[bin], 1u);
    }
    __syncthreads();
    unsigned* gh = hist + (size_t)b * NBINS;
    for (int i = threadIdx.x; i < NBINS; i += 256)
        if (h[i]) atomicAdd(&gh[i], h[i]);
}

// ---------------------------------------------------------------------------
// K2: per-batch cut bin = max bin with count(bins >= bin) >= TOPK
__global__ void findcut_kernel(const unsigned* __restrict__ hist,
                               int* __restrict__ cutbin) {
    int b = threadIdx.x;
    if (b < B_) {
        const unsigned* h = hist + (size_t)b * NBINS;
        unsigned acc = 0;
        int cb = 0;
        for (int bin = NBINS - 1; bin >= 0; --bin) {
            acc += h[bin];
            if (acc >= (unsigned)TOPK) { cb = bin; break; }
        }
        cutbin[b] = cb;
    }
}

// ---------------------------------------------------------------------------
// K3: compact candidates (bin >= cut) as sortable keys:
//     key = (score_bits << 32) | (0xFFFFFFFF - flat_idx)
//     descending key order == lax.top_k order (score desc, index asc)
__global__ __launch_bounds__(256) void compact_kernel(const float* __restrict__ scores,
                                                      const int* __restrict__ cutbin,
                                                      unsigned* __restrict__ candCount,
                                                      unsigned long long* __restrict__ candKeys) {
    int b = blockIdx.x;
    int chunk = blockIdx.y;
    int cb = cutbin[b];
    const float* s = scores + (size_t)b * NC;
    unsigned long long* ck = candKeys + (size_t)b * CANDCAP;
    int start = chunk * CHUNK;
    int end = start + CHUNK;
    for (int i = start + threadIdx.x; i < end; i += 256) {
        float v = s[i];
        v = (v > 0.001f) ? v : 0.0f;
        int bin = (int)(v * 4096.0f);
        bin = bin > (NBINS - 1) ? (NBINS - 1) : bin;
        if (bin >= cb) {
            unsigned pos = atomicAdd(&candCount[b], 1u);
            if (pos < (unsigned)CANDCAP) {
                unsigned sb = __float_as_uint(v);
                ck[pos] = ((unsigned long long)sb << 32) |
                          (unsigned long long)(0xFFFFFFFFu - (unsigned)i);
            }
        }
    }
}

// ---------------------------------------------------------------------------
// K4: per-batch bitonic sort (descending) of 4096 keys in LDS; gather top-1024
__global__ __launch_bounds__(1024) void sort_gather_kernel(
        const unsigned long long* __restrict__ candKeys,
        const unsigned* __restrict__ candCount,
        const float* __restrict__ boxes,
        float* __restrict__ topScore,
        float* __restrict__ topBox,
        int* __restrict__ topCls) {
    __shared__ unsigned long long k[CANDCAP];
    int b = blockIdx.x;
    unsigned M = candCount[b];
    if (M > (unsigned)CANDCAP) M = CANDCAP;
    const unsigned long long* ck = candKeys + (size_t)b * CANDCAP;
    for (int i = threadIdx.x; i < CANDCAP; i += 1024)
        k[i] = (i < (int)M) ? ck[i] : 0ull;
    __syncthreads();
    for (int kk = 2; kk <= CANDCAP; kk <<= 1) {
        for (int j = kk >> 1; j > 0; j >>= 1) {
            for (int t = threadIdx.x; t < CANDCAP; t += 1024) {
                int l = t ^ j;
                if (l > t) {
                    unsigned long long a = k[t], c = k[l];
                    bool sw = ((t & kk) == 0) ? (a < c) : (a > c);  // descending
                    if (sw) { k[t] = c; k[l] = a; }
                }
            }
            __syncthreads();
        }
    }
    int i = threadIdx.x;   // 0..1023 — top 1024
    unsigned long long key = k[i];
    float sc = __uint_as_float((unsigned)(key >> 32));
    unsigned idx = 0xFFFFFFFFu - (unsigned)(key & 0xFFFFFFFFull);
    if (idx >= (unsigned)NC) idx = 0;       // defensive (padding keys)
    unsigned bi = idx / (unsigned)C_;
    unsigned cl = idx % (unsigned)C_;
    const float* bp = boxes + (size_t)b * N_ * 4 + (size_t)bi * 4;
    float c0 = bp[0], c1 = bp[1], c2 = bp[2], c3 = bp[3];
    topScore[b * TOPK + i] = sc;
    float* tb = topBox + ((size_t)b * TOPK + i) * 4;
    tb[0] = c0; tb[1] = c1; tb[2] = c2; tb[3] = c3;
    topCls[b * TOPK + i] = (int)cl;
}

// ---------------------------------------------------------------------------
// K5: per-class greedy NMS (cross-class IoU is exactly 0: offset 4096 >> 640).
// One thread per class. IoU replicated in f32 with __fmul_rn to block FMA
// contraction (must match numpy f32 op-for-op at the iou > 0.7 decision).
__global__ __launch_bounds__(128) void nms_kernel(const float* __restrict__ topScore,
                                                  const float* __restrict__ topBox,
                                                  const int* __restrict__ topCls,
                                                  int* __restrict__ keep) {
    __shared__ float bx[TOPK][4];
    __shared__ float ssc[TOPK];
    __shared__ short scl[TOPK];
    int b = blockIdx.x;
    for (int i = threadIdx.x; i < TOPK; i += 128) {
        const float* tb = topBox + ((size_t)b * TOPK + i) * 4;
        bx[i][0] = tb[0]; bx[i][1] = tb[1]; bx[i][2] = tb[2]; bx[i][3] = tb[3];
        ssc[i] = topScore[b * TOPK + i];
        scl[i] = (short)topCls[b * TOPK + i];
    }
    __syncthreads();
    int c = threadIdx.x;
    if (c < C_) {
        float off = (float)c * 4096.0f;     // exact
        unsigned short kidx[160];
        int nk = 0;
        for (int i = 0; i < TOPK; ++i) {
            if (scl[i] != (short)c) continue;
            int kp;
            if (!(ssc[i] > 0.001f)) {
                kp = 0;                      // keep0 false: never kept, never suppresses
            } else {
                float y1 = bx[i][0] + off, x1 = bx[i][1] + off;
                float y2 = bx[i][2] + off, x2 = bx[i][3] + off;
                float area_i = __fmul_rn((x2 - x1) + 1.0f, (y2 - y1) + 1.0f);
                kp = 1;
                for (int t = 0; t < nk; ++t) {
                    int j = kidx[t];
                    float jy1 = bx[j][0] + off, jx1 = bx[j][1] + off;
                    float jy2 = bx[j][2] + off, jx2 = bx[j][3] + off;
                    float area_j = __fmul_rn((jx2 - jx1) + 1.0f, (jy2 - jy1) + 1.0f);
                    float yy1 = fmaxf(jy1, y1), xx1 = fmaxf(jx1, x1);
                    float yy2 = fminf(jy2, y2), xx2 = fminf(jx2, x2);
                    float w = fmaxf(0.0f, (xx2 - xx1) + 1.0f);
                    float h = fmaxf(0.0f, (yy2 - yy1) + 1.0f);
                    float inter = __fmul_rn(w, h);
                    float denom = (area_i + area_j) - inter;
                    float iou = inter / denom;
                    if (iou > 0.7f) { kp = 0; break; }
                }
                if (kp && nk < 160) kidx[nk++] = (unsigned short)i;
            }
            keep[b * TOPK + i] = kp;
        }
    }
}

// ---------------------------------------------------------------------------
// K6: stable top-300 of final_scores: kept positions in order, then suppressed
// positions in order (score-0 ties break by lower index). Write all outputs.
__global__ __launch_bounds__(1024) void finalize_kernel(const float* __restrict__ topScore,
                                                        const float* __restrict__ topBox,
                                                        const int* __restrict__ topCls,
                                                        const int* __restrict__ keep,
                                                        float* __restrict__ out) {
    __shared__ int sk[TOPK];
    __shared__ int sel[MAXDET];
    int b = blockIdx.x;
    int i = threadIdx.x;
    int kp = keep[b * TOPK + i];
    sk[i] = kp;
    __syncthreads();
    // inclusive Hillis-Steele scan over 1024
    for (int off = 1; off < TOPK; off <<= 1) {
        int add = (i >= off) ? sk[i - off] : 0;
        __syncthreads();
        sk[i] += add;
        __syncthreads();
    }
    int nk = sk[TOPK - 1];
    int incl = sk[i];
    int kexcl = incl - kp;       // exclusive kept rank
    int sexcl = i - kexcl;       // exclusive suppressed rank
    if (kp) {
        if (kexcl < MAXDET) sel[kexcl] = i;
    } else {
        int slot = nk + sexcl;
        if (slot < MAXDET) sel[slot] = i;
    }
    __syncthreads();
    if (i < MAXDET) {
        int p = sel[i];
        float sc = (i < nk) ? topScore[b * TOPK + p] : 0.0f;
        const float* tb = topBox + ((size_t)b * TOPK + p) * 4;
        float* ob = out + ((size_t)b * MAXDET + i) * 4;
        ob[0] = tb[0]; ob[1] = tb[1]; ob[2] = tb[2]; ob[3] = tb[3];
        out[OUT_SCORES + b * MAXDET + i] = sc;
        out[OUT_LABELS + b * MAXDET + i] = (float)topCls[b * TOPK + p];
    }
    if (i == 0) out[OUT_NVALID + b] = (float)(nk < MAXDET ? nk : MAXDET);
}

// ---------------------------------------------------------------------------
extern "C" void kernel_launch(void* const* d_in, const int* in_sizes, int n_in,
                              void* d_out, int out_size, void* d_ws, size_t ws_size,
                              hipStream_t stream) {
    const float* boxes  = (const float*)d_in[0];   // (32, 8400, 4)
    const float* scores = (const float*)d_in[1];   // (32, 8400, 80)
    float* out = (float*)d_out;
    char* ws = (char*)d_ws;

    unsigned* hist = (unsigned*)(ws + WS_HIST);
    unsigned* candCount = (unsigned*)(ws + WS_CANDCNT);
    int* cutbin = (int*)(ws + WS_CUTBIN);
    unsigned long long* candKeys = (unsigned long long*)(ws + WS_CANDKEYS);
    float* topScore = (float*)(ws + WS_TOPSCORE);
    float* topBox = (float*)(ws + WS_TOPBOX);
    int* topCls = (int*)(ws + WS_TOPCLS);
    int* keep = (int*)(ws + WS_KEEP);

    // zero histogram + candidate counters (ws is poisoned to 0xAA each call)
    hipMemsetAsync(ws, 0, WS_CUTBIN, stream);

    hist_kernel<<<dim3(B_, NCHUNK), 256, 0, stream>>>(scores, hist);
    findcut_kernel<<<1, 64, 0, stream>>>(hist, cutbin);
    compact_kernel<<<dim3(B_, NCHUNK), 256, 0, stream>>>(scores, cutbin, candCount, candKeys);
    sort_gather_kernel<<<B_, 1024, 0, stream>>>(candKeys, candCount, boxes,
                                                topScore, topBox, topCls);
    nms_kernel<<<B_, 128, 0, stream>>>(topScore, topBox, topCls, keep);
    finalize_kernel<<<B_, 1024, 0, stream>>>(topScore, topBox, topCls, keep, out);
}

// Round 2
// 445.261 us; speedup vs baseline: 4.2224x; 4.2224x over previous
//
#include <hip/hip_runtime.h>
#include <cstdint>
#include <cstddef>

// Problem constants (fixed by the reference)
#define B_      32
#define N_      8400
#define C_      80
#define NC      672000        // N_*C_
#define NBINS   4096
#define TOPK    1024
#define MAXDET  300
#define CANDCAP 4096
#define CHUNK   16000
#define NCHUNK  42            // 42*16000 == 672000
#define CLS_CAP 256           // max candidates per (batch,class); actual ~13

// Workspace layout (bytes)
#define WS_HIST      0              // 32*4096*4  = 524288
#define WS_CANDCNT   524288         // 32*4       = 128
#define WS_CUTBIN    524416         // 32*4       = 128
#define WS_CANDKEYS  524544         // 32*4096*8  = 1048576
#define WS_TOPSCORE  1573120        // 32*1024*4  = 131072
#define WS_TOPBOX    1704192        // 32*1024*16 = 524288
#define WS_TOPCLS    2228480        // 32*1024*4  = 131072
#define WS_KEEP      2359552        // 32*1024*4  = 131072
#define WS_TOTAL     2490624

// Output layout (float32, concatenated): boxes[32][300][4], scores[32][300],
// labels[32][300], n_valid[32]
#define OUT_SCORES  38400
#define OUT_LABELS  48000
#define OUT_NVALID  57600

// ---------------------------------------------------------------------------
// K1: per-batch histogram of bin = floor(v*4096), v = (s > 0.001 ? s : 0)
__global__ __launch_bounds__(256) void hist_kernel(const float* __restrict__ scores,
                                                   unsigned* __restrict__ hist) {
    __shared__ unsigned h[NBINS];
    int b = blockIdx.x;
    int chunk = blockIdx.y;
    for (int i = threadIdx.x; i < NBINS; i += 256) h[i] = 0;
    __syncthreads();
    const float* s = scores + (size_t)b * NC;
    int start = chunk * CHUNK;
    int end = start + CHUNK;
    for (int i = start + threadIdx.x; i < end; i += 256) {
        float v = s[i];
        v = (v > 0.001f) ? v : 0.0f;
        int bin = (int)(v * 4096.0f);       // exact: v * 2^12
        bin = bin > (NBINS - 1) ? (NBINS - 1) : bin;
        atomicAdd(&h[bin], 1u);
    }
    __syncthreads();
    unsigned* gh = hist + (size_t)b * NBINS;
    for (int i = threadIdx.x; i < NBINS; i += 256)
        if (h[i]) atomicAdd(&gh[i], h[i]);
}

// ---------------------------------------------------------------------------
// K2: per-batch cut bin = max bin with count(bins >= bin) >= TOPK
__global__ void findcut_kernel(const unsigned* __restrict__ hist,
                               int* __restrict__ cutbin) {
    int b = threadIdx.x;
    if (b < B_) {
        const unsigned* h = hist + (size_t)b * NBINS;
        unsigned acc = 0;
        int cb = 0;
        for (int bin = NBINS - 1; bin >= 0; --bin) {
            acc += h[bin];
            if (acc >= (unsigned)TOPK) { cb = bin; break; }
        }
        cutbin[b] = cb;
    }
}

// ---------------------------------------------------------------------------
// K3: compact candidates (bin >= cut) as sortable keys:
//     key = (score_bits << 32) | (0xFFFFFFFF - flat_idx)
//     descending key order == lax.top_k order (score desc, index asc)
__global__ __launch_bounds__(256) void compact_kernel(const float* __restrict__ scores,
                                                      const int* __restrict__ cutbin,
                                                      unsigned* __restrict__ candCount,
                                                      unsigned long long* __restrict__ candKeys) {
    int b = blockIdx.x;
    int chunk = blockIdx.y;
    int cb = cutbin[b];
    const float* s = scores + (size_t)b * NC;
    unsigned long long* ck = candKeys + (size_t)b * CANDCAP;
    int start = chunk * CHUNK;
    int end = start + CHUNK;
    for (int i = start + threadIdx.x; i < end; i += 256) {
        float v = s[i];
        v = (v > 0.001f) ? v : 0.0f;
        int bin = (int)(v * 4096.0f);
        bin = bin > (NBINS - 1) ? (NBINS - 1) : bin;
        if (bin >= cb) {
            unsigned pos = atomicAdd(&candCount[b], 1u);
            if (pos < (unsigned)CANDCAP) {
                unsigned sb = __float_as_uint(v);
                ck[pos] = ((unsigned long long)sb << 32) |
                          (unsigned long long)(0xFFFFFFFFu - (unsigned)i);
            }
        }
    }
}

// ---------------------------------------------------------------------------
// K4: per-batch bitonic sort (descending) of 4096 keys in LDS; gather top-1024
__global__ __launch_bounds__(1024) void sort_gather_kernel(
        const unsigned long long* __restrict__ candKeys,
        const unsigned* __restrict__ candCount,
        const float* __restrict__ boxes,
        float* __restrict__ topScore,
        float* __restrict__ topBox,
        int* __restrict__ topCls) {
    __shared__ unsigned long long k[CANDCAP];
    int b = blockIdx.x;
    unsigned M = candCount[b];
    if (M > (unsigned)CANDCAP) M = CANDCAP;
    const unsigned long long* ck = candKeys + (size_t)b * CANDCAP;
    for (int i = threadIdx.x; i < CANDCAP; i += 1024)
        k[i] = (i < (int)M) ? ck[i] : 0ull;
    __syncthreads();
    for (int kk = 2; kk <= CANDCAP; kk <<= 1) {
        for (int j = kk >> 1; j > 0; j >>= 1) {
            for (int t = threadIdx.x; t < CANDCAP; t += 1024) {
                int l = t ^ j;
                if (l > t) {
                    unsigned long long a = k[t], c = k[l];
                    bool sw = ((t & kk) == 0) ? (a < c) : (a > c);  // descending
                    if (sw) { k[t] = c; k[l] = a; }
                }
            }
            __syncthreads();
        }
    }
    int i = threadIdx.x;   // 0..1023 — top 1024
    unsigned long long key = k[i];
    float sc = __uint_as_float((unsigned)(key >> 32));
    unsigned idx = 0xFFFFFFFFu - (unsigned)(key & 0xFFFFFFFFull);
    if (idx >= (unsigned)NC) idx = 0;       // defensive (padding keys)
    unsigned bi = idx / (unsigned)C_;
    unsigned cl = idx % (unsigned)C_;
    const float* bp = boxes + (size_t)b * N_ * 4 + (size_t)bi * 4;
    float c0 = bp[0], c1 = bp[1], c2 = bp[2], c3 = bp[3];
    topScore[b * TOPK + i] = sc;
    float* tb = topBox + ((size_t)b * TOPK + i) * 4;
    tb[0] = c0; tb[1] = c1; tb[2] = c2; tb[3] = c3;
    topCls[b * TOPK + i] = (int)cl;
}

// ---------------------------------------------------------------------------
// K5: per-(batch,class) greedy NMS, one 64-thread block per (b,c).
// Cross-class IoU is exactly 0 (offset gap 4096 >> max box 640), so per-class
// greedy NMS is exactly equivalent to the reference's global sequential loop.
// Ballot-compaction preserves score order; wave-parallel suppression.
// IoU replicated in f32 with __fmul_rn to block FMA contraction.
__global__ __launch_bounds__(64) void nms_kernel(const float* __restrict__ topScore,
                                                 const float* __restrict__ topBox,
                                                 const int* __restrict__ topCls,
                                                 int* __restrict__ keep) {
    __shared__ unsigned short pos[CLS_CAP];
    __shared__ float by1[CLS_CAP], bx1[CLS_CAP], by2[CLS_CAP], bx2[CLS_CAP];
    __shared__ float barea[CLS_CAP];
    __shared__ unsigned char sup[CLS_CAP];
    int b = blockIdx.x;
    int c = blockIdx.y;
    int lane = threadIdx.x;
    const float* ts = topScore + b * TOPK;
    const int*   tc = topCls + b * TOPK;
    int*         kp = keep + b * TOPK;
    float off = (float)c * 4096.0f;         // exact
    int base = 0;
    for (int chunkS = 0; chunkS < TOPK; chunkS += 64) {
        int i = chunkS + lane;
        int cls = tc[i];
        float sc = ts[i];
        bool mine = (cls == c);
        bool listed = mine && (sc > 0.001f);
        if (mine) kp[i] = 0;                 // default; kept ones overwritten below
        unsigned long long mask = __ballot(listed);
        int rank = __popcll(mask & ((1ull << lane) - 1ull));
        if (listed) {
            int slot = base + rank;
            if (slot < CLS_CAP) {
                pos[slot] = (unsigned short)i;
                const float* tb = topBox + ((size_t)(b * TOPK + i)) * 4;
                float y1 = tb[0] + off, x1 = tb[1] + off;
                float y2 = tb[2] + off, x2 = tb[3] + off;
                by1[slot] = y1; bx1[slot] = x1; by2[slot] = y2; bx2[slot] = x2;
                barea[slot] = __fmul_rn((x2 - x1) + 1.0f, (y2 - y1) + 1.0f);
                sup[slot] = 0;
            }
        }
        base += __popcll(mask);
    }
    int m = base < CLS_CAP ? base : CLS_CAP;
    __syncthreads();
    int cur = 0;
    while (cur < m) {
        // invariant: slot `cur` is unsuppressed -> kept
        if (lane == 0) kp[pos[cur]] = 1;
        float cy1 = by1[cur], cx1 = bx1[cur], cy2 = by2[cur], cx2 = bx2[cur];
        float carea = barea[cur];
        for (int j = cur + 1 + lane; j < m; j += 64) {
            if (!sup[j]) {
                float yy1 = fmaxf(cy1, by1[j]), xx1 = fmaxf(cx1, bx1[j]);
                float yy2 = fminf(cy2, by2[j]), xx2 = fminf(cx2, bx2[j]);
                float w = fmaxf(0.0f, (xx2 - xx1) + 1.0f);
                float h = fmaxf(0.0f, (yy2 - yy1) + 1.0f);
                float inter = __fmul_rn(w, h);
                float denom = (carea + barea[j]) - inter;
                float iou = inter / denom;
                if (iou > 0.7f) sup[j] = 1;
            }
        }
        __syncthreads();
        int nxt = m;
        for (int j = cur + 1 + lane; j < m; j += 64)
            if (!sup[j]) { nxt = j; break; }
        for (int o = 32; o > 0; o >>= 1) {
            int other = __shfl_xor(nxt, o, 64);
            nxt = nxt < other ? nxt : other;
        }
        cur = nxt;
    }
}

// ---------------------------------------------------------------------------
// K6: stable top-300 of final_scores: kept positions in order, then suppressed
// positions in order (score-0 ties break by lower index). Write all outputs.
__global__ __launch_bounds__(1024) void finalize_kernel(const float* __restrict__ topScore,
                                                        const float* __restrict__ topBox,
                                                        const int* __restrict__ topCls,
                                                        const int* __restrict__ keep,
                                                        float* __restrict__ out) {
    __shared__ int sk[TOPK];
    __shared__ int sel[MAXDET];
    int b = blockIdx.x;
    int i = threadIdx.x;
    int kp = keep[b * TOPK + i];
    sk[i] = kp;
    __syncthreads();
    // inclusive Hillis-Steele scan over 1024
    for (int off = 1; off < TOPK; off <<= 1) {
        int add = (i >= off) ? sk[i - off] : 0;
        __syncthreads();
        sk[i] += add;
        __syncthreads();
    }
    int nk = sk[TOPK - 1];
    int incl = sk[i];
    int kexcl = incl - kp;       // exclusive kept rank
    int sexcl = i - kexcl;       // exclusive suppressed rank
    if (kp) {
        if (kexcl < MAXDET) sel[kexcl] = i;
    } else {
        int slot = nk + sexcl;
        if (slot < MAXDET) sel[slot] = i;
    }
    __syncthreads();
    if (i < MAXDET) {
        int p = sel[i];
        float sc = (i < nk) ? topScore[b * TOPK + p] : 0.0f;
        const float* tb = topBox + ((size_t)b * TOPK + p) * 4;
        float* ob = out + ((size_t)b * MAXDET + i) * 4;
        ob[0] = tb[0]; ob[1] = tb[1]; ob[2] = tb[2]; ob[3] = tb[3];
        out[OUT_SCORES + b * MAXDET + i] = sc;
        out[OUT_LABELS + b * MAXDET + i] = (float)topCls[b * TOPK + p];
    }
    if (i == 0) out[OUT_NVALID + b] = (float)(nk < MAXDET ? nk : MAXDET);
}

// ---------------------------------------------------------------------------
extern "C" void kernel_launch(void* const* d_in, const int* in_sizes, int n_in,
                              void* d_out, int out_size, void* d_ws, size_t ws_size,
                              hipStream_t stream) {
    const float* boxes  = (const float*)d_in[0];   // (32, 8400, 4)
    const float* scores = (const float*)d_in[1];   // (32, 8400, 80)
    float* out = (float*)d_out;
    char* ws = (char*)d_ws;

    unsigned* hist = (unsigned*)(ws + WS_HIST);
    unsigned* candCount = (unsigned*)(ws + WS_CANDCNT);
    int* cutbin = (int*)(ws + WS_CUTBIN);
    unsigned long long* candKeys = (unsigned long long*)(ws + WS_CANDKEYS);
    float* topScore = (float*)(ws + WS_TOPSCORE);
    float* topBox = (float*)(ws + WS_TOPBOX);
    int* topCls = (int*)(ws + WS_TOPCLS);
    int* keep = (int*)(ws + WS_KEEP);

    // zero histogram + candidate counters (ws is poisoned to 0xAA each call)
    hipMemsetAsync(ws, 0, WS_CUTBIN, stream);

    hist_kernel<<<dim3(B_, NCHUNK), 256, 0, stream>>>(scores, hist);
    findcut_kernel<<<1, 64, 0, stream>>>(hist, cutbin);
    compact_kernel<<<dim3(B_, NCHUNK), 256, 0, stream>>>(scores, cutbin, candCount, candKeys);
    sort_gather_kernel<<<B_, 1024, 0, stream>>>(candKeys, candCount, boxes,
                                                topScore, topBox, topCls);
    nms_kernel<<<dim3(B_, C_), 64, 0, stream>>>(topScore, topBox, topCls, keep);
    finalize_kernel<<<B_, 1024, 0, stream>>>(topScore, topBox, topCls, keep, out);
}

// Round 3
// 224.709 us; speedup vs baseline: 8.3667x; 1.9815x over previous
//
#include <hip/hip_runtime.h>
#include <cstdint>
#include <cstddef>

// Problem constants (fixed by the reference)
#define B_      32
#define N_      8400
#define C_      80
#define NC      672000        // N_*C_
#define NCV4    168000        // NC/4
#define NBINS   4096
#define TOPK    1024
#define MAXDET  300
#define CANDCAP 4096
#define NSLICE  16
#define SLICE_V4 10500        // NCV4 / NSLICE
#define STAGE_CAP 1024        // per-block LDS staging for compact (~75 typical)

// Workspace layout (bytes)
#define WS_HIST      0              // 32*16*4096*2 = 4194304 (ushort slices)
#define WS_CANDCNT   4194304        // 32*4   = 128
#define WS_CANDKEYS  4194432        // 32*4096*8 = 1048576
#define WS_TOPSCORE  5243008        // 32*1024*4  = 131072
#define WS_TOPBOX    5374080        // 32*1024*16 = 524288
#define WS_TOPCLS    5898368        // 32*1024*4  = 131072
#define WS_KEEP      6029440        // 32*1024*4  = 131072
#define WS_TOTAL     6160512

// Output layout (float32, concatenated): boxes[32][300][4], scores[32][300],
// labels[32][300], n_valid[32]
#define OUT_SCORES  38400
#define OUT_LABELS  48000
#define OUT_NVALID  57600

__device__ __forceinline__ int score_bin(float v) {
    v = (v > 0.001f) ? v : 0.0f;
    int bin = (int)(v * 4096.0f);        // exact: v * 2^12
    return bin > (NBINS - 1) ? (NBINS - 1) : bin;
}

// ---------------------------------------------------------------------------
// K1: per-(batch,slice) histogram of bin = floor(v*4096), v=(s>0.001?s:0).
// Private ushort slice per block, plain stores — NO global atomics.
// Slice has 42000 elements < 65536 so ushort cannot overflow.
__global__ __launch_bounds__(256) void hist_kernel(const float4* __restrict__ scores4,
                                                   unsigned short* __restrict__ hist,
                                                   unsigned* __restrict__ candCount) {
    __shared__ unsigned h[NBINS];
    int b = blockIdx.x;
    int sl = blockIdx.y;
    for (int i = threadIdx.x; i < NBINS; i += 256) h[i] = 0;
    if (sl == 0 && threadIdx.x == 0) candCount[b] = 0;  // replaces memset
    __syncthreads();
    const float4* s = scores4 + (size_t)b * NCV4 + (size_t)sl * SLICE_V4;
    for (int i = threadIdx.x; i < SLICE_V4; i += 256) {
        float4 v = s[i];
        atomicAdd(&h[score_bin(v.x)], 1u);
        atomicAdd(&h[score_bin(v.y)], 1u);
        atomicAdd(&h[score_bin(v.z)], 1u);
        atomicAdd(&h[score_bin(v.w)], 1u);
    }
    __syncthreads();
    unsigned short* gh = hist + ((size_t)b * NSLICE + sl) * NBINS;
    for (int i = threadIdx.x; i < NBINS; i += 256)
        gh[i] = (unsigned short)h[i];
}

// ---------------------------------------------------------------------------
// K2: fused findcut + compact. Each block recomputes its batch's cut bin
// (cheap: 256 threads × 16 slice loads), then compacts candidates into an LDS
// staging buffer and reserves ONE contiguous global range per block.
// key = (score_bits<<32) | (~flat_idx): desc key order == lax.top_k order.
__global__ __launch_bounds__(256) void compact_kernel(const float4* __restrict__ scores4,
                                                      const unsigned short* __restrict__ hist,
                                                      unsigned* __restrict__ candCount,
                                                      unsigned long long* __restrict__ candKeys) {
    __shared__ unsigned long long stage[STAGE_CAP];
    __shared__ unsigned cnt256[256];
    __shared__ unsigned lcnt;
    __shared__ int s_cut;
    __shared__ unsigned sbase;
    int b = blockIdx.x;
    int sl = blockIdx.y;
    int tid = threadIdx.x;
    const unsigned short* hb = hist + (size_t)b * NSLICE * NBINS;

    // --- cut bin: thread t sums bin (4095 - t) across 16 slices
    {
        int bin = NBINS - 1 - tid;
        unsigned ssum = 0;
        #pragma unroll
        for (int t = 0; t < NSLICE; ++t) ssum += hb[t * NBINS + bin];
        cnt256[tid] = ssum;
        if (tid == 0) lcnt = 0;
    }
    __syncthreads();
    if (tid == 0) {
        unsigned acc = 0;
        int cb = 0;
        bool found = false;
        for (int t = 0; t < 256; ++t) {
            acc += cnt256[t];
            if (acc >= (unsigned)TOPK) { cb = NBINS - 1 - t; found = true; break; }
        }
        if (!found) {   // degenerate-input fallback (never hit on bench input)
            for (int bin = NBINS - 1 - 256; bin >= 0; --bin) {
                unsigned ssum = 0;
                for (int t = 0; t < NSLICE; ++t) ssum += hb[t * NBINS + bin];
                acc += ssum;
                if (acc >= (unsigned)TOPK) { cb = bin; break; }
            }
        }
        s_cut = cb;
    }
    __syncthreads();
    int cb = s_cut;

    // --- compact this slice into LDS staging
    const float4* s = scores4 + (size_t)b * NCV4 + (size_t)sl * SLICE_V4;
    unsigned long long* ck = candKeys + (size_t)b * CANDCAP;
    for (int i = tid; i < SLICE_V4; i += 256) {
        float4 v = s[i];
        float c[4] = {v.x, v.y, v.z, v.w};
        unsigned flat0 = ((unsigned)sl * SLICE_V4 + (unsigned)i) * 4u;
        #pragma unroll
        for (int kc = 0; kc < 4; ++kc) {
            float x = (c[kc] > 0.001f) ? c[kc] : 0.0f;
            int bin = (int)(x * 4096.0f);
            bin = bin > (NBINS - 1) ? (NBINS - 1) : bin;
            if (bin >= cb) {
                unsigned long long key =
                    ((unsigned long long)__float_as_uint(x) << 32) |
                    (unsigned long long)(0xFFFFFFFFu - (flat0 + kc));
                unsigned p = atomicAdd(&lcnt, 1u);
                if (p < (unsigned)STAGE_CAP) stage[p] = key;
                else {  // staging overflow fallback: direct global (rare)
                    unsigned gp = atomicAdd(&candCount[b], 1u);
                    if (gp < (unsigned)CANDCAP) ck[gp] = key;
                }
            }
        }
    }
    __syncthreads();
    unsigned n = lcnt < (unsigned)STAGE_CAP ? lcnt : (unsigned)STAGE_CAP;
    if (tid == 0) sbase = atomicAdd(&candCount[b], n);   // ONE atomic per block
    __syncthreads();
    unsigned basep = sbase;
    for (unsigned i = tid; i < n; i += 256) {
        unsigned gp = basep + i;
        if (gp < (unsigned)CANDCAP) ck[gp] = stage[i];
    }
}

// ---------------------------------------------------------------------------
// K4: per-batch bitonic sort (descending) in LDS; size tiered by M; gather top-1024
__global__ __launch_bounds__(1024) void sort_gather_kernel(
        const unsigned long long* __restrict__ candKeys,
        const unsigned* __restrict__ candCount,
        const float* __restrict__ boxes,
        float* __restrict__ topScore,
        float* __restrict__ topBox,
        int* __restrict__ topCls) {
    __shared__ unsigned long long k[CANDCAP];
    int b = blockIdx.x;
    unsigned M = candCount[b];
    if (M > (unsigned)CANDCAP) M = CANDCAP;
    int S = (M <= 1024u) ? 1024 : (M <= 2048u ? 2048 : CANDCAP);
    const unsigned long long* ck = candKeys + (size_t)b * CANDCAP;
    for (int i = threadIdx.x; i < S; i += 1024)
        k[i] = (i < (int)M) ? ck[i] : 0ull;
    __syncthreads();
    for (int kk = 2; kk <= S; kk <<= 1) {
        for (int j = kk >> 1; j > 0; j >>= 1) {
            for (int t = threadIdx.x; t < S; t += 1024) {
                int l = t ^ j;
                if (l > t) {
                    unsigned long long a = k[t], c = k[l];
                    bool sw = ((t & kk) == 0) ? (a < c) : (a > c);  // descending
                    if (sw) { k[t] = c; k[l] = a; }
                }
            }
            __syncthreads();
        }
    }
    int i = threadIdx.x;   // 0..1023 — top 1024
    unsigned long long key = k[i];
    float sc = __uint_as_float((unsigned)(key >> 32));
    unsigned idx = 0xFFFFFFFFu - (unsigned)(key & 0xFFFFFFFFull);
    if (idx >= (unsigned)NC) idx = 0;       // defensive (padding keys)
    unsigned bi = idx / (unsigned)C_;
    unsigned cl = idx % (unsigned)C_;
    const float* bp = boxes + (size_t)b * N_ * 4 + (size_t)bi * 4;
    float c0 = bp[0], c1 = bp[1], c2 = bp[2], c3 = bp[3];
    topScore[b * TOPK + i] = sc;
    float* tb = topBox + ((size_t)b * TOPK + i) * 4;
    tb[0] = c0; tb[1] = c1; tb[2] = c2; tb[3] = c3;
    topCls[b * TOPK + i] = (int)cl;
}

// ---------------------------------------------------------------------------
// K5: per-(batch,class) greedy NMS, one 64-thread block per (b,c).
// Cross-class IoU is exactly 0 (offset gap 4096 >> max box 640), so per-class
// greedy NMS is exactly equivalent to the reference's global sequential loop.
// Ballot-compaction preserves score order; wave-parallel suppression.
// IoU replicated in f32 with __fmul_rn to block FMA contraction.
#define CLS_CAP 256
__global__ __launch_bounds__(64) void nms_kernel(const float* __restrict__ topScore,
                                                 const float* __restrict__ topBox,
                                                 const int* __restrict__ topCls,
                                                 int* __restrict__ keep) {
    __shared__ unsigned short pos[CLS_CAP];
    __shared__ float by1[CLS_CAP], bx1[CLS_CAP], by2[CLS_CAP], bx2[CLS_CAP];
    __shared__ float barea[CLS_CAP];
    __shared__ unsigned char sup[CLS_CAP];
    int b = blockIdx.x;
    int c = blockIdx.y;
    int lane = threadIdx.x;
    const float* ts = topScore + b * TOPK;
    const int*   tc = topCls + b * TOPK;
    int*         kp = keep + b * TOPK;
    float off = (float)c * 4096.0f;         // exact
    int base = 0;
    for (int chunkS = 0; chunkS < TOPK; chunkS += 64) {
        int i = chunkS + lane;
        int cls = tc[i];
        float sc = ts[i];
        bool mine = (cls == c);
        bool listed = mine && (sc > 0.001f);
        if (mine) kp[i] = 0;                 // default; kept ones overwritten below
        unsigned long long mask = __ballot(listed);
        int rank = __popcll(mask & ((1ull << lane) - 1ull));
        if (listed) {
            int slot = base + rank;
            if (slot < CLS_CAP) {
                pos[slot] = (unsigned short)i;
                const float* tb = topBox + ((size_t)(b * TOPK + i)) * 4;
                float y1 = tb[0] + off, x1 = tb[1] + off;
                float y2 = tb[2] + off, x2 = tb[3] + off;
                by1[slot] = y1; bx1[slot] = x1; by2[slot] = y2; bx2[slot] = x2;
                barea[slot] = __fmul_rn((x2 - x1) + 1.0f, (y2 - y1) + 1.0f);
                sup[slot] = 0;
            }
        }
        base += __popcll(mask);
    }
    int m = base < CLS_CAP ? base : CLS_CAP;
    __syncthreads();
    int cur = 0;
    while (cur < m) {
        // invariant: slot `cur` is unsuppressed -> kept
        if (lane == 0) kp[pos[cur]] = 1;
        float cy1 = by1[cur], cx1 = bx1[cur], cy2 = by2[cur], cx2 = bx2[cur];
        float carea = barea[cur];
        for (int j = cur + 1 + lane; j < m; j += 64) {
            if (!sup[j]) {
                float yy1 = fmaxf(cy1, by1[j]), xx1 = fmaxf(cx1, bx1[j]);
                float yy2 = fminf(cy2, by2[j]), xx2 = fminf(cx2, bx2[j]);
                float w = fmaxf(0.0f, (xx2 - xx1) + 1.0f);
                float h = fmaxf(0.0f, (yy2 - yy1) + 1.0f);
                float inter = __fmul_rn(w, h);
                float denom = (carea + barea[j]) - inter;
                float iou = inter / denom;
                if (iou > 0.7f) sup[j] = 1;
            }
        }
        __syncthreads();
        int nxt = m;
        for (int j = cur + 1 + lane; j < m; j += 64)
            if (!sup[j]) { nxt = j; break; }
        for (int o = 32; o > 0; o >>= 1) {
            int other = __shfl_xor(nxt, o, 64);
            nxt = nxt < other ? nxt : other;
        }
        cur = nxt;
    }
}

// ---------------------------------------------------------------------------
// K6: stable top-300 of final_scores: kept positions in order, then suppressed
// positions in order (score-0 ties break by lower index). Write all outputs.
__global__ __launch_bounds__(1024) void finalize_kernel(const float* __restrict__ topScore,
                                                        const float* __restrict__ topBox,
                                                        const int* __restrict__ topCls,
                                                        const int* __restrict__ keep,
                                                        float* __restrict__ out) {
    __shared__ int sk[TOPK];
    __shared__ int sel[MAXDET];
    int b = blockIdx.x;
    int i = threadIdx.x;
    int kp = keep[b * TOPK + i];
    sk[i] = kp;
    __syncthreads();
    // inclusive Hillis-Steele scan over 1024
    for (int off = 1; off < TOPK; off <<= 1) {
        int add = (i >= off) ? sk[i - off] : 0;
        __syncthreads();
        sk[i] += add;
        __syncthreads();
    }
    int nk = sk[TOPK - 1];
    int incl = sk[i];
    int kexcl = incl - kp;       // exclusive kept rank
    int sexcl = i - kexcl;       // exclusive suppressed rank
    if (kp) {
        if (kexcl < MAXDET) sel[kexcl] = i;
    } else {
        int slot = nk + sexcl;
        if (slot < MAXDET) sel[slot] = i;
    }
    __syncthreads();
    if (i < MAXDET) {
        int p = sel[i];
        float sc = (i < nk) ? topScore[b * TOPK + p] : 0.0f;
        const float* tb = topBox + ((size_t)b * TOPK + p) * 4;
        float* ob = out + ((size_t)b * MAXDET + i) * 4;
        ob[0] = tb[0]; ob[1] = tb[1]; ob[2] = tb[2]; ob[3] = tb[3];
        out[OUT_SCORES + b * MAXDET + i] = sc;
        out[OUT_LABELS + b * MAXDET + i] = (float)topCls[b * TOPK + p];
    }
    if (i == 0) out[OUT_NVALID + b] = (float)(nk < MAXDET ? nk : MAXDET);
}

// ---------------------------------------------------------------------------
extern "C" void kernel_launch(void* const* d_in, const int* in_sizes, int n_in,
                              void* d_out, int out_size, void* d_ws, size_t ws_size,
                              hipStream_t stream) {
    const float* boxes  = (const float*)d_in[0];   // (32, 8400, 4)
    const float* scores = (const float*)d_in[1];   // (32, 8400, 80)
    float* out = (float*)d_out;
    char* ws = (char*)d_ws;

    unsigned short* hist = (unsigned short*)(ws + WS_HIST);
    unsigned* candCount = (unsigned*)(ws + WS_CANDCNT);
    unsigned long long* candKeys = (unsigned long long*)(ws + WS_CANDKEYS);
    float* topScore = (float*)(ws + WS_TOPSCORE);
    float* topBox = (float*)(ws + WS_TOPBOX);
    int* topCls = (int*)(ws + WS_TOPCLS);
    int* keep = (int*)(ws + WS_KEEP);

    const float4* scores4 = (const float4*)scores;

    hist_kernel<<<dim3(B_, NSLICE), 256, 0, stream>>>(scores4, hist, candCount);
    compact_kernel<<<dim3(B_, NSLICE), 256, 0, stream>>>(scores4, hist, candCount, candKeys);
    sort_gather_kernel<<<B_, 1024, 0, stream>>>(candKeys, candCount, boxes,
                                                topScore, topBox, topCls);
    nms_kernel<<<dim3(B_, C_), 64, 0, stream>>>(topScore, topBox, topCls, keep);
    finalize_kernel<<<B_, 1024, 0, stream>>>(topScore, topBox, topCls, keep, out);
}

// Round 4
// 202.318 us; speedup vs baseline: 9.2926x; 1.1107x over previous
//
#include <hip/hip_runtime.h>
#include <cstdint>
#include <cstddef>

// Problem constants (fixed by the reference)
#define B_      32
#define N_      8400
#define C_      80
#define NC      672000        // N_*C_
#define NCV4    168000        // NC/4
#define NBINS   4096
#define TOPK    1024
#define MAXDET  300
#define CANDCAP 4096
#define NSLICE  16
#define SLICE_V4 10500        // NCV4 / NSLICE
#define STAGE_CAP 1024        // per-block LDS staging (~82 expected per slice)
#define CC_STRIDE 32          // candCount padded: one 128B line per batch

// Static stage threshold: bin 4088 -> score >= 4088/4096 = 0.998046875.
// Expected candidates/batch = 672000*8/4096 = 1312 (sd ~36): >=1024 and
// <=4096 with overwhelming margin on uniform scores. Any input violating
// this takes the exact in-kernel fallback path in sort_gather_kernel.
#define STAGE_THRESH 0.998046875f

// Workspace layout (bytes)
#define WS_CANDCNT   0              // 32*32*4   = 4096 (padded counters)
#define WS_CANDKEYS  4096           // 32*4096*8 = 1048576
#define WS_TOPSCORE  1052672        // 32*1024*4  = 131072
#define WS_TOPBOX    1183744        // 32*1024*16 = 524288
#define WS_TOPCLS    1708032        // 32*1024*4  = 131072
#define WS_KEEP      1839104        // 32*1024*4  = 131072
#define WS_TOTAL     1970176

// Output layout (float32, concatenated): boxes[32][300][4], scores[32][300],
// labels[32][300], n_valid[32]
#define OUT_SCORES  38400
#define OUT_LABELS  48000
#define OUT_NVALID  57600

// ---------------------------------------------------------------------------
// K1: single-pass filter+stage. Stages every element with
// v=(s>0.001?s:0) >= STAGE_THRESH as key = (bits(v)<<32) | ~flat_idx
// (descending key order == lax.top_k order: score desc, index asc).
// One contiguous global reservation per block; per-batch counters padded to
// separate cache lines (no cross-XCD line ping-pong).
__global__ __launch_bounds__(256) void stage_kernel(const float4* __restrict__ scores4,
                                                    unsigned* __restrict__ candCount,
                                                    unsigned long long* __restrict__ candKeys) {
    __shared__ unsigned long long stage[STAGE_CAP];
    __shared__ unsigned lcnt;
    __shared__ unsigned sbase;
    int b = blockIdx.x;
    int sl = blockIdx.y;
    int tid = threadIdx.x;
    if (tid == 0) lcnt = 0;
    __syncthreads();
    const float4* s = scores4 + (size_t)b * NCV4 + (size_t)sl * SLICE_V4;
    unsigned long long* ck = candKeys + (size_t)b * CANDCAP;
    unsigned* cc = &candCount[b * CC_STRIDE];
    for (int i = tid; i < SLICE_V4; i += 256) {
        float4 v = s[i];
        float c[4] = {v.x, v.y, v.z, v.w};
        unsigned flat0 = ((unsigned)sl * SLICE_V4 + (unsigned)i) * 4u;
        #pragma unroll
        for (int kc = 0; kc < 4; ++kc) {
            float x = (c[kc] > 0.001f) ? c[kc] : 0.0f;
            if (x >= STAGE_THRESH) {
                unsigned long long key =
                    ((unsigned long long)__float_as_uint(x) << 32) |
                    (unsigned long long)(0xFFFFFFFFu - (flat0 + kc));
                unsigned p = atomicAdd(&lcnt, 1u);
                if (p < (unsigned)STAGE_CAP) stage[p] = key;
                else {  // LDS staging overflow (rare): direct global spill
                    unsigned gp = atomicAdd(cc, 1u);
                    if (gp < (unsigned)CANDCAP) ck[gp] = key;
                }
            }
        }
    }
    __syncthreads();
    unsigned n = lcnt < (unsigned)STAGE_CAP ? lcnt : (unsigned)STAGE_CAP;
    if (tid == 0) sbase = atomicAdd(cc, n);   // ONE atomic per block
    __syncthreads();
    unsigned basep = sbase;
    for (unsigned i = tid; i < n; i += 256) {
        unsigned gp = basep + i;
        if (gp < (unsigned)CANDCAP) ck[gp] = stage[i];
    }
}

// ---------------------------------------------------------------------------
// K2: per-batch bitonic sort (descending) in LDS + gather top-1024.
// Fast path: sort the staged candidates (exact superset of top-1024 when
// TOPK <= M <= CANDCAP). Fallback (M out of range, never on uniform input):
// this block rebuilds a histogram of its batch from scores, finds the exact
// cut bin, restages into LDS, then sorts — fully self-contained, exact.
__global__ __launch_bounds__(1024) void sort_gather_kernel(
        const float4* __restrict__ scores4,
        const unsigned long long* __restrict__ candKeys,
        const unsigned* __restrict__ candCount,
        const float* __restrict__ boxes,
        float* __restrict__ topScore,
        float* __restrict__ topBox,
        int* __restrict__ topCls) {
    __shared__ unsigned long long k[CANDCAP];
    __shared__ unsigned fhist[NBINS];      // fallback only
    __shared__ unsigned scnt;
    __shared__ int s_cut;
    int b = blockIdx.x;
    int tid = threadIdx.x;
    unsigned M = candCount[b * CC_STRIDE];
    bool fb = (M < (unsigned)TOPK) || (M > (unsigned)CANDCAP);
    int S;
    if (!fb) {
        S = (M <= 1024u) ? 1024 : (M <= 2048u ? 2048 : CANDCAP);
        const unsigned long long* ck = candKeys + (size_t)b * CANDCAP;
        for (int i = tid; i < S; i += 1024)
            k[i] = (i < (int)M) ? ck[i] : 0ull;
        __syncthreads();
    } else {
        // --- exact fallback: histogram -> cut -> restage (slow, correct)
        for (int i = tid; i < NBINS; i += 1024) fhist[i] = 0;
        if (tid == 0) scnt = 0;
        __syncthreads();
        const float4* s = scores4 + (size_t)b * NCV4;
        for (int i = tid; i < NCV4; i += 1024) {
            float4 v = s[i];
            float c[4] = {v.x, v.y, v.z, v.w};
            #pragma unroll
            for (int kc = 0; kc < 4; ++kc) {
                float x = (c[kc] > 0.001f) ? c[kc] : 0.0f;
                int bin = (int)(x * 4096.0f);
                bin = bin > (NBINS - 1) ? (NBINS - 1) : bin;
                atomicAdd(&fhist[bin], 1u);
            }
        }
        __syncthreads();
        if (tid == 0) {
            unsigned acc = 0;
            int cb = 0;
            for (int bin = NBINS - 1; bin >= 0; --bin) {
                acc += fhist[bin];
                if (acc >= (unsigned)TOPK) { cb = bin; break; }
            }
            s_cut = cb;
        }
        __syncthreads();
        int cb = s_cut;
        for (int i = tid; i < NCV4; i += 1024) {
            float4 v = s[i];
            float c[4] = {v.x, v.y, v.z, v.w};
            unsigned flat0 = (unsigned)i * 4u;
            #pragma unroll
            for (int kc = 0; kc < 4; ++kc) {
                float x = (c[kc] > 0.001f) ? c[kc] : 0.0f;
                int bin = (int)(x * 4096.0f);
                bin = bin > (NBINS - 1) ? (NBINS - 1) : bin;
                if (bin >= cb) {
                    unsigned p = atomicAdd(&scnt, 1u);
                    if (p < (unsigned)CANDCAP)
                        k[p] = ((unsigned long long)__float_as_uint(x) << 32) |
                               (unsigned long long)(0xFFFFFFFFu - (flat0 + kc));
                }
            }
        }
        __syncthreads();
        unsigned M2 = scnt < (unsigned)CANDCAP ? scnt : (unsigned)CANDCAP;
        S = (M2 <= 1024u) ? 1024 : (M2 <= 2048u ? 2048 : CANDCAP);
        for (int i = tid; i < S; i += 1024)
            if (i >= (int)M2) k[i] = 0ull;
        __syncthreads();
    }
    // --- bitonic sort, descending
    for (int kk = 2; kk <= S; kk <<= 1) {
        for (int j = kk >> 1; j > 0; j >>= 1) {
            for (int t = tid; t < S; t += 1024) {
                int l = t ^ j;
                if (l > t) {
                    unsigned long long a = k[t], c = k[l];
                    bool sw = ((t & kk) == 0) ? (a < c) : (a > c);
                    if (sw) { k[t] = c; k[l] = a; }
                }
            }
            __syncthreads();
        }
    }
    int i = tid;   // 0..1023 — top 1024
    unsigned long long key = k[i];
    float sc = __uint_as_float((unsigned)(key >> 32));
    unsigned idx = 0xFFFFFFFFu - (unsigned)(key & 0xFFFFFFFFull);
    if (idx >= (unsigned)NC) idx = 0;       // defensive (padding keys)
    unsigned bi = idx / (unsigned)C_;
    unsigned cl = idx % (unsigned)C_;
    const float* bp = boxes + (size_t)b * N_ * 4 + (size_t)bi * 4;
    float c0 = bp[0], c1 = bp[1], c2 = bp[2], c3 = bp[3];
    topScore[b * TOPK + i] = sc;
    float* tb = topBox + ((size_t)b * TOPK + i) * 4;
    tb[0] = c0; tb[1] = c1; tb[2] = c2; tb[3] = c3;
    topCls[b * TOPK + i] = (int)cl;
}

// ---------------------------------------------------------------------------
// K3: per-(batch,class) greedy NMS, one 64-thread block per (b,c).
// Cross-class IoU is exactly 0 (offset gap 4096 >> max box 640), so per-class
// greedy NMS is exactly equivalent to the reference's global sequential loop.
// Ballot-compaction preserves score order; wave-parallel suppression.
// IoU replicated in f32 with __fmul_rn to block FMA contraction.
#define CLS_CAP 256
__global__ __launch_bounds__(64) void nms_kernel(const float* __restrict__ topScore,
                                                 const float* __restrict__ topBox,
                                                 const int* __restrict__ topCls,
                                                 int* __restrict__ keep) {
    __shared__ unsigned short pos[CLS_CAP];
    __shared__ float by1[CLS_CAP], bx1[CLS_CAP], by2[CLS_CAP], bx2[CLS_CAP];
    __shared__ float barea[CLS_CAP];
    __shared__ unsigned char sup[CLS_CAP];
    int b = blockIdx.x;
    int c = blockIdx.y;
    int lane = threadIdx.x;
    const float* ts = topScore + b * TOPK;
    const int*   tc = topCls + b * TOPK;
    int*         kp = keep + b * TOPK;
    float off = (float)c * 4096.0f;         // exact
    int base = 0;
    for (int chunkS = 0; chunkS < TOPK; chunkS += 64) {
        int i = chunkS + lane;
        int cls = tc[i];
        float sc = ts[i];
        bool mine = (cls == c);
        bool listed = mine && (sc > 0.001f);
        if (mine) kp[i] = 0;                 // default; kept ones overwritten below
        unsigned long long mask = __ballot(listed);
        int rank = __popcll(mask & ((1ull << lane) - 1ull));
        if (listed) {
            int slot = base + rank;
            if (slot < CLS_CAP) {
                pos[slot] = (unsigned short)i;
                const float* tb = topBox + ((size_t)(b * TOPK + i)) * 4;
                float y1 = tb[0] + off, x1 = tb[1] + off;
                float y2 = tb[2] + off, x2 = tb[3] + off;
                by1[slot] = y1; bx1[slot] = x1; by2[slot] = y2; bx2[slot] = x2;
                barea[slot] = __fmul_rn((x2 - x1) + 1.0f, (y2 - y1) + 1.0f);
                sup[slot] = 0;
            }
        }
        base += __popcll(mask);
    }
    int m = base < CLS_CAP ? base : CLS_CAP;
    __syncthreads();
    int cur = 0;
    while (cur < m) {
        // invariant: slot `cur` is unsuppressed -> kept
        if (lane == 0) kp[pos[cur]] = 1;
        float cy1 = by1[cur], cx1 = bx1[cur], cy2 = by2[cur], cx2 = bx2[cur];
        float carea = barea[cur];
        for (int j = cur + 1 + lane; j < m; j += 64) {
            if (!sup[j]) {
                float yy1 = fmaxf(cy1, by1[j]), xx1 = fmaxf(cx1, bx1[j]);
                float yy2 = fminf(cy2, by2[j]), xx2 = fminf(cx2, bx2[j]);
                float w = fmaxf(0.0f, (xx2 - xx1) + 1.0f);
                float h = fmaxf(0.0f, (yy2 - yy1) + 1.0f);
                float inter = __fmul_rn(w, h);
                float denom = (carea + barea[j]) - inter;
                float iou = inter / denom;
                if (iou > 0.7f) sup[j] = 1;
            }
        }
        __syncthreads();
        int nxt = m;
        for (int j = cur + 1 + lane; j < m; j += 64)
            if (!sup[j]) { nxt = j; break; }
        for (int o = 32; o > 0; o >>= 1) {
            int other = __shfl_xor(nxt, o, 64);
            nxt = nxt < other ? nxt : other;
        }
        cur = nxt;
    }
}

// ---------------------------------------------------------------------------
// K4: stable top-300 of final_scores: kept positions in order, then suppressed
// positions in order (score-0 ties break by lower index). Write all outputs.
__global__ __launch_bounds__(1024) void finalize_kernel(const float* __restrict__ topScore,
                                                        const float* __restrict__ topBox,
                                                        const int* __restrict__ topCls,
                                                        const int* __restrict__ keep,
                                                        float* __restrict__ out) {
    __shared__ int sk[TOPK];
    __shared__ int sel[MAXDET];
    int b = blockIdx.x;
    int i = threadIdx.x;
    int kp = keep[b * TOPK + i];
    sk[i] = kp;
    __syncthreads();
    // inclusive Hillis-Steele scan over 1024
    for (int off = 1; off < TOPK; off <<= 1) {
        int add = (i >= off) ? sk[i - off] : 0;
        __syncthreads();
        sk[i] += add;
        __syncthreads();
    }
    int nk = sk[TOPK - 1];
    int incl = sk[i];
    int kexcl = incl - kp;       // exclusive kept rank
    int sexcl = i - kexcl;       // exclusive suppressed rank
    if (kp) {
        if (kexcl < MAXDET) sel[kexcl] = i;
    } else {
        int slot = nk + sexcl;
        if (slot < MAXDET) sel[slot] = i;
    }
    __syncthreads();
    if (i < MAXDET) {
        int p = sel[i];
        float sc = (i < nk) ? topScore[b * TOPK + p] : 0.0f;
        const float* tb = topBox + ((size_t)b * TOPK + p) * 4;
        float* ob = out + ((size_t)b * MAXDET + i) * 4;
        ob[0] = tb[0]; ob[1] = tb[1]; ob[2] = tb[2]; ob[3] = tb[3];
        out[OUT_SCORES + b * MAXDET + i] = sc;
        out[OUT_LABELS + b * MAXDET + i] = (float)topCls[b * TOPK + p];
    }
    if (i == 0) out[OUT_NVALID + b] = (float)(nk < MAXDET ? nk : MAXDET);
}

// ---------------------------------------------------------------------------
extern "C" void kernel_launch(void* const* d_in, const int* in_sizes, int n_in,
                              void* d_out, int out_size, void* d_ws, size_t ws_size,
                              hipStream_t stream) {
    const float* boxes  = (const float*)d_in[0];   // (32, 8400, 4)
    const float* scores = (const float*)d_in[1];   // (32, 8400, 80)
    float* out = (float*)d_out;
    char* ws = (char*)d_ws;

    unsigned* candCount = (unsigned*)(ws + WS_CANDCNT);
    unsigned long long* candKeys = (unsigned long long*)(ws + WS_CANDKEYS);
    float* topScore = (float*)(ws + WS_TOPSCORE);
    float* topBox = (float*)(ws + WS_TOPBOX);
    int* topCls = (int*)(ws + WS_TOPCLS);
    int* keep = (int*)(ws + WS_KEEP);

    const float4* scores4 = (const float4*)scores;

    // zero the padded per-batch counters (ws is poisoned 0xAA each call)
    hipMemsetAsync(candCount, 0, B_ * CC_STRIDE * sizeof(unsigned), stream);

    stage_kernel<<<dim3(B_, NSLICE), 256, 0, stream>>>(scores4, candCount, candKeys);
    sort_gather_kernel<<<B_, 1024, 0, stream>>>(scores4, candKeys, candCount, boxes,
                                                topScore, topBox, topCls);
    nms_kernel<<<dim3(B_, C_), 64, 0, stream>>>(topScore, topBox, topCls, keep);
    finalize_kernel<<<B_, 1024, 0, stream>>>(topScore, topBox, topCls, keep, out);
}